// Round 9
// baseline (209.535 us; speedup 1.0000x reference)
//
#include <hip/hip_runtime.h>
#include <cstdint>

// BinarizedLeNet5 / CIFAR10, B=2048.  Round 10.
//  k1  : r8 body + o-loop unroll 4 (wider FMA window per s_load burst so the
//        scheduler can pipeline the scalar weight stream across channels).
//  kBCD: k3+k45 merged (grid 1024, 2 samples/block). Stage B = k3 2-sample
//        body verbatim, ballots -> LDS li2 (proven form, r5 fused kernel);
//        stage C/D = k45 fc1/fc2/fc3 verbatim reading li2 from LDS (proven).
//        Saves one launch+gap and the ws2 global roundtrip; conv2 popc waves
//        overlap fc1's L2 weight stream across blocks.
//  k0 unchanged. All per-output float op order identical -> absmax 0.0.
//  Budget (r7 fixed-floor 103.5us): k1 ~47, k3+k45+gaps ~49, k0 ~5.

#define BSZ 2048

__device__ __forceinline__ float sgnf(float w) {
    return (w > 0.f) ? 1.f : ((w < 0.f) ? -1.f : 0.f);
}

// ---------------- k0: all packing ----------------
__global__ __launch_bounds__(256) void k0_pack(
    const float* __restrict__ c1w, const float* __restrict__ c2w,
    const float* __restrict__ f1w, const float* __restrict__ f2w,
    const float* __restrict__ c1b, const float* __restrict__ c2b,
    const float* __restrict__ f1b, const float* __restrict__ f2b,
    const float* __restrict__ b1g, const float* __restrict__ b1b,
    const float* __restrict__ b1m, const float* __restrict__ b1v,
    const float* __restrict__ b2g, const float* __restrict__ b2b,
    const float* __restrict__ b2m, const float* __restrict__ b2v,
    const float* __restrict__ b3g, const float* __restrict__ b3b,
    const float* __restrict__ b3m, const float* __restrict__ b3v,
    const float* __restrict__ b4g, const float* __restrict__ b4b,
    const float* __restrict__ b4m, const float* __restrict__ b4v,
    float* __restrict__ sw1, uint32_t* __restrict__ wp2,
    uint32_t* __restrict__ wpf1, uint32_t* __restrict__ wpf2,
    float* __restrict__ bnp2, float* __restrict__ bnp3,
    float* __restrict__ bnp4) {
    int bid = blockIdx.x, t = threadIdx.x;
    if (bid < 1024) {
        // fc1 pack: wave W covers 512 consecutive elements of row o.
        int W = bid * 4 + (t >> 6), l = t & 63;
        int o = W >> 3, chunk = W & 7;
        const float* row = f1w + (size_t)o * 4096 + chunk * 512;
        int kwb = chunk * 16;
#pragma unroll
        for (int j = 0; j < 8; j++) {
            float vj = row[j * 64 + l];
            unsigned long long mk = __ballot(vj > 0.f);
            if (l == 0) {
                wpf1[(size_t)(kwb + 2 * j) * 512 + o] = (uint32_t)mk;
                wpf1[(size_t)(kwb + 2 * j + 1) * 512 + o] = (uint32_t)(mk >> 32);
            }
        }
    } else if (bid == 1024) {
        // conv2 pack: wp2[o*16+k]: k<9 = weight bits, k=9..15 = precomputed
        // border-correction constants {R0,R2,C0,C2,t0,t2,(t6|t8<<16)}.
        __shared__ uint32_t wloc[576];
        for (int i = t; i < 576; i += 256) {
            int o = i / 9, k = i - o * 9;
            uint32_t word = 0;
            for (int c = 0; c < 32; c++)
                if (c2w[(o * 32 + c) * 9 + k] > 0.f) word |= (1u << c);
            wloc[i] = word;
        }
        __syncthreads();
        for (int i = t; i < 1024; i += 256) {
            int o = i >> 4, k = i & 15;
            const uint32_t* wr = wloc + o * 9;
            uint32_t outv;
            if (k < 9) {
                outv = wr[k];
            } else {
                int tv[9];
#pragma unroll
                for (int j = 0; j < 9; j++) tv[j] = 32 - 2 * __popc(wr[j]);
                int v = 0;
                if (k == 9)  v = tv[0] + tv[1] + tv[2];            // R0
                if (k == 10) v = tv[6] + tv[7] + tv[8];            // R2
                if (k == 11) v = tv[0] + tv[3] + tv[6];            // C0
                if (k == 12) v = tv[2] + tv[5] + tv[8];            // C2
                if (k == 13) v = tv[0];                            // t0
                if (k == 14) v = tv[2];                            // t2
                if (k == 15)
                    v = (int)(((uint32_t)(uint16_t)tv[6]) |
                              ((uint32_t)(uint16_t)tv[8] << 16));  // t6|t8
                outv = (uint32_t)v;
            }
            wp2[i] = outv;
        }
        if (t < 64) {
            float inv = __fdiv_rn(b2g[t], __fsqrt_rn(b2v[t] + 1e-5f));
            float add = __fsub_rn(b2b[t], __fmul_rn(b2m[t], inv));
            bnp2[t * 4] = inv; bnp2[t * 4 + 1] = add;
            bnp2[t * 4 + 2] = c2b[t]; bnp2[t * 4 + 3] = 0.f;
        }
    } else if (bid == 1025) {
        // conv1 signed weights, bn folded into slots 28..30 of each 32-row.
        for (int i = t; i < 1024; i += 256) {
            int o = i >> 5, r = i & 31;
            float val;
            if (r < 27) {
                val = sgnf(c1w[o * 27 + r]);
            } else if (r == 28 || r == 29 || r == 30) {
                float inv = __fdiv_rn(b1g[o], __fsqrt_rn(b1v[o] + 1e-5f));
                float add = __fsub_rn(b1b[o], __fmul_rn(b1m[o], inv));
                val = (r == 28) ? inv : ((r == 29) ? add : c1b[o]);
            } else {
                val = 0.f;
            }
            sw1[i] = val;
        }
    } else if (bid < 1042) {
        // fc2 pack: wpf2[k*256+o]
        int i = (bid - 1026) * 256 + t;       // 4096 = [16 k][256 o]
        int k = i >> 8, o = i & 255;
        const float* r = f2w + (size_t)o * 512 + k * 32;
        uint32_t word = 0;
#pragma unroll
        for (int j = 0; j < 32; j++)
            if (r[j] > 0.f) word |= (1u << j);
        wpf2[k * 256 + o] = word;
    } else {
        // bn3 + bn4 params (with fc biases folded in slot .z)
        for (int i = t; i < 512; i += 256) {
            float inv = __fdiv_rn(b3g[i], __fsqrt_rn(b3v[i] + 1e-5f));
            float add = __fsub_rn(b3b[i], __fmul_rn(b3m[i], inv));
            bnp3[i * 4] = inv; bnp3[i * 4 + 1] = add;
            bnp3[i * 4 + 2] = f1b[i]; bnp3[i * 4 + 3] = 0.f;
        }
        if (t < 256) {
            float inv = __fdiv_rn(b4g[t], __fsqrt_rn(b4v[t] + 1e-5f));
            float add = __fsub_rn(b4b[t], __fmul_rn(b4m[t], inv));
            bnp4[t * 4] = inv; bnp4[t * 4 + 1] = add;
            bnp4[t * 4 + 2] = f2b[t]; bnp4[t * 4 + 3] = 0.f;
        }
    }
}

// ---------------- k1: conv1 + pool + bn1 + sign-pack ----------------
// grid 2048, thread = 1 pooled pixel. Border-only LDS zeroing, float2 gathers,
// weights+bn from one s_load base, o-loop unroll 4.
__global__ __launch_bounds__(256) void k1_conv1(
    const float* __restrict__ x, const float* __restrict__ sw,
    uint32_t* __restrict__ out) {
    int b = blockIdx.x, t = threadIdx.x;
    const int TS = 36;                       // tile row stride (words)
    __shared__ float tile[3 * 34 * TS];      // rows 0..33 = conv rows -1..32
    // border zeroing: rows 0,33 cols 0..33; cols 0,33 rows 1..32  (132/channel)
#pragma unroll
    for (int q = 0; q < 2; q++) {
        int i = q * 256 + t;
        if (i < 396) {
            int c = i / 132, r = i - c * 132;
            int row, col;
            if (r < 34)      { row = 0;      col = r; }
            else if (r < 68) { row = 33;     col = r - 34; }
            else if (r < 100){ row = r - 67; col = 0; }
            else             { row = r - 99; col = 33; }
            tile[c * (34 * TS) + row * TS + col] = 0.f;
        }
    }
#pragma unroll
    for (int q = 0; q < 3; q++) {            // 768 float4 = 3 per thread
        int idx = q * 256 + t;
        int c = idx >> 8, rem = idx & 255;
        int r = rem >> 3, c4 = rem & 7;
        float4 v = ((const float4*)(x + ((size_t)b * 3 + c) * 1024 + r * 32))[c4];
        float* dst = tile + c * (34 * TS) + (r + 1) * TS + c4 * 4 + 1;
        dst[0] = v.x; dst[1] = v.y; dst[2] = v.z; dst[3] = v.w;
    }
    __syncthreads();
    int py = t >> 4, px = t & 15;
    float in[48];
#pragma unroll
    for (int c = 0; c < 3; c++)
#pragma unroll
        for (int i = 0; i < 4; i++) {
            int base = c * (34 * TS) + (2 * py + i) * TS + 2 * px;
            float2 v01 = *(const float2*)&tile[base];
            float2 v23 = *(const float2*)&tile[base + 2];
            in[c * 16 + i * 4]     = v01.x;
            in[c * 16 + i * 4 + 1] = v01.y;
            in[c * 16 + i * 4 + 2] = v23.x;
            in[c * 16 + i * 4 + 3] = v23.y;
        }
    uint32_t word = 0;
#pragma unroll 4
    for (int o = 0; o < 32; o++) {
        const float* wo = sw + o * 32;           // uniform -> s_load (x16 pairs)
        float a00 = 0.f, a01 = 0.f, a10 = 0.f, a11 = 0.f;
#pragma unroll
        for (int c = 0; c < 3; c++)
#pragma unroll
            for (int ky = 0; ky < 3; ky++)
#pragma unroll
                for (int kx = 0; kx < 3; kx++) {
                    float wv = wo[c * 9 + ky * 3 + kx];
                    a00 = fmaf(in[c * 16 + ky * 4 + kx], wv, a00);
                    a01 = fmaf(in[c * 16 + ky * 4 + kx + 1], wv, a01);
                    a10 = fmaf(in[c * 16 + (ky + 1) * 4 + kx], wv, a10);
                    a11 = fmaf(in[c * 16 + (ky + 1) * 4 + kx + 1], wv, a11);
                }
        float4 p = *(const float4*)(wo + 28);    // {inv, add, bias, 0}
        float mx = fmaxf(fmaxf(a00, a01), fmaxf(a10, a11));
        float h = __fadd_rn(mx, p.z);
        float val = __fadd_rn(__fmul_rn(h, p.x), p.y);
        word |= (val > 0.f) ? (1u << o) : 0u;
    }
    out[(size_t)b * 256 + t] = word;
}

// ---------------- conv2 helper (unchanged) ----------------
__device__ __forceinline__ int conv2_mi(
    const uint32_t* val,
    uint32_t w0, uint32_t w1, uint32_t w2, uint32_t w3, uint32_t w4,
    uint32_t w5, uint32_t w6, uint32_t w7, uint32_t w8,
    int R0, int R2, int C0, int C2, int t0, int t2, int t6, int t8,
    bool top, bool bot, bool lef, bool rig,
    bool ctl, bool ctr, bool cbl, bool cbr) {
    int P00 = __popc(val[0] ^ w0) + __popc(val[1] ^ w1) + __popc(val[2] ^ w2) +
              __popc(val[4] ^ w3) + __popc(val[5] ^ w4) + __popc(val[6] ^ w5) +
              __popc(val[8] ^ w6) + __popc(val[9] ^ w7) + __popc(val[10] ^ w8);
    int P01 = __popc(val[1] ^ w0) + __popc(val[2] ^ w1) + __popc(val[3] ^ w2) +
              __popc(val[5] ^ w3) + __popc(val[6] ^ w4) + __popc(val[7] ^ w5) +
              __popc(val[9] ^ w6) + __popc(val[10] ^ w7) + __popc(val[11] ^ w8);
    int P10 = __popc(val[4] ^ w0) + __popc(val[5] ^ w1) + __popc(val[6] ^ w2) +
              __popc(val[8] ^ w3) + __popc(val[9] ^ w4) + __popc(val[10] ^ w5) +
              __popc(val[12] ^ w6) + __popc(val[13] ^ w7) + __popc(val[14] ^ w8);
    int P11 = __popc(val[5] ^ w0) + __popc(val[6] ^ w1) + __popc(val[7] ^ w2) +
              __popc(val[9] ^ w3) + __popc(val[10] ^ w4) + __popc(val[11] ^ w5) +
              __popc(val[13] ^ w6) + __popc(val[14] ^ w7) + __popc(val[15] ^ w8);
    int s00 = 288 - 2 * P00 - ((top ? R0 : 0) + (lef ? C0 : 0) - (ctl ? t0 : 0));
    int s01 = 288 - 2 * P01 - ((top ? R0 : 0) + (rig ? C2 : 0) - (ctr ? t2 : 0));
    int s10 = 288 - 2 * P10 - ((bot ? R2 : 0) + (lef ? C0 : 0) - (cbl ? t6 : 0));
    int s11 = 288 - 2 * P11 - ((bot ? R2 : 0) + (rig ? C2 : 0) - (cbr ? t8 : 0));
    return max(max(s00, s01), max(s10, s11));
}

// ---------------- kBCD: conv2 + fc1 + fc2 + fc3, 2 samples/block ----------------
__global__ __launch_bounds__(256) void kBCD(
    const uint32_t* __restrict__ in, const uint32_t* __restrict__ wp2,
    const float* __restrict__ bnp2, const uint32_t* __restrict__ wpf1,
    const float* __restrict__ bnp3, const uint32_t* __restrict__ wpf2,
    const float* __restrict__ bnp4, const float* __restrict__ f3w,
    const float* __restrict__ f3b, float* __restrict__ out) {
    int t = threadIdx.x;
    int b0 = blockIdx.x * 2;
    const int P = 19;
    __shared__ uint32_t tile[2][18 * 19];
    __shared__ uint32_t li2[2][128];
    __shared__ uint32_t li3[2][16];
    __shared__ float hbuf[2][256];

    // ---- stage B: conv2 xnor-popc + pool + bn2 + sign (k3 2-sample body) ----
    {
        uint32_t* tf = &tile[0][0];
        for (int i = t; i < 2 * 18 * 19; i += 256) tf[i] = 0;
        __syncthreads();
        {
            int y = t >> 4, xx = t & 15;
#pragma unroll
            for (int s = 0; s < 2; s++)
                tile[s][(y + 1) * P + xx + 1] = in[(size_t)(b0 + s) * 256 + t];
        }
        __syncthreads();
        int wv = t >> 6, l = t & 63;
        int py = l >> 3, px = l & 7;
        uint32_t va[16], vb[16];
#pragma unroll
        for (int i = 0; i < 4; i++)
#pragma unroll
            for (int j = 0; j < 4; j++) {
                va[i * 4 + j] = tile[0][(2 * py + i) * P + 2 * px + j];
                vb[i * 4 + j] = tile[1][(2 * py + i) * P + 2 * px + j];
            }
        bool top = (py == 0), bot = (py == 7), lef = (px == 0), rig = (px == 7);
        bool ctl = top && lef, ctr = top && rig, cbl = bot && lef, cbr = bot && rig;
#pragma unroll 2
        for (int oi = 0; oi < 16; oi++) {
            int o = __builtin_amdgcn_readfirstlane(wv * 16 + oi);  // force SGPR
            const uint32_t* wo = wp2 + o * 16;
            uint32_t w0 = wo[0], w1 = wo[1], w2 = wo[2], w3 = wo[3], w4 = wo[4],
                     w5 = wo[5], w6 = wo[6], w7 = wo[7], w8 = wo[8];
            int R0 = (int)wo[9], R2 = (int)wo[10], C0 = (int)wo[11], C2 = (int)wo[12];
            int t0 = (int)wo[13], t2 = (int)wo[14];
            int pk = (int)wo[15];
            int t6 = (int)(short)(pk & 0xffff);
            int t8 = pk >> 16;
            float4 p = ((const float4*)bnp2)[o];
            int miA = conv2_mi(va, w0, w1, w2, w3, w4, w5, w6, w7, w8,
                               R0, R2, C0, C2, t0, t2, t6, t8,
                               top, bot, lef, rig, ctl, ctr, cbl, cbr);
            float hA = __fadd_rn((float)miA, p.z);
            float bvA = __fadd_rn(__fmul_rn(hA, p.x), p.y);
            unsigned long long mkA = __ballot(bvA > 0.f);
            int miB = conv2_mi(vb, w0, w1, w2, w3, w4, w5, w6, w7, w8,
                               R0, R2, C0, C2, t0, t2, t6, t8,
                               top, bot, lef, rig, ctl, ctr, cbl, cbr);
            float hB = __fadd_rn((float)miB, p.z);
            float bvB = __fadd_rn(__fmul_rn(hB, p.x), p.y);
            unsigned long long mkB = __ballot(bvB > 0.f);
            if (l == 0) {
                li2[0][2 * o] = (uint32_t)mkA;
                li2[0][2 * o + 1] = (uint32_t)(mkA >> 32);
                li2[1][2 * o] = (uint32_t)mkB;
                li2[1][2 * o + 1] = (uint32_t)(mkB >> 32);
            }
        }
    }
    __syncthreads();

    // ---- stage C: fc1 xnor-popc + bn3 + sign (k45 body, li2 from LDS) ----
    {
        int o1 = t, o2 = t + 256;
        float4 p1 = ((const float4*)bnp3)[o1];
        float4 p2 = ((const float4*)bnp3)[o2];
        int a00 = 0, a01 = 0, a10 = 0, a11 = 0;   // a[sample][o1/o2]
#pragma unroll 8
        for (int k = 0; k < 128; k++) {
            uint32_t wA = wpf1[k * 512 + o1];     // coalesced
            uint32_t wB = wpf1[k * 512 + o2];     // coalesced
            uint32_t s0 = li2[0][k], s1 = li2[1][k];  // LDS broadcast
            a00 += __popc(wA ^ s0);
            a10 += __popc(wA ^ s1);
            a01 += __popc(wB ^ s0);
            a11 += __popc(wB ^ s1);
        }
        int wv = t >> 6, l = t & 63;
        {   // sample 0, outputs [wv*64,..) -> words 2wv, 2wv+1
            float h = __fadd_rn((float)(4096 - 2 * a00), p1.z);
            float bv = __fadd_rn(__fmul_rn(h, p1.x), p1.y);
            unsigned long long mk = __ballot(bv > 0.f);
            if (l == 0) { li3[0][2 * wv] = (uint32_t)mk;
                          li3[0][2 * wv + 1] = (uint32_t)(mk >> 32); }
        }
        {   // sample 0, outputs [256+wv*64,..) -> words 8+2wv, 8+2wv+1
            float h = __fadd_rn((float)(4096 - 2 * a01), p2.z);
            float bv = __fadd_rn(__fmul_rn(h, p2.x), p2.y);
            unsigned long long mk = __ballot(bv > 0.f);
            if (l == 0) { li3[0][8 + 2 * wv] = (uint32_t)mk;
                          li3[0][8 + 2 * wv + 1] = (uint32_t)(mk >> 32); }
        }
        {   // sample 1, o1
            float h = __fadd_rn((float)(4096 - 2 * a10), p1.z);
            float bv = __fadd_rn(__fmul_rn(h, p1.x), p1.y);
            unsigned long long mk = __ballot(bv > 0.f);
            if (l == 0) { li3[1][2 * wv] = (uint32_t)mk;
                          li3[1][2 * wv + 1] = (uint32_t)(mk >> 32); }
        }
        {   // sample 1, o2
            float h = __fadd_rn((float)(4096 - 2 * a11), p2.z);
            float bv = __fadd_rn(__fmul_rn(h, p2.x), p2.y);
            unsigned long long mk = __ballot(bv > 0.f);
            if (l == 0) { li3[1][8 + 2 * wv] = (uint32_t)mk;
                          li3[1][8 + 2 * wv + 1] = (uint32_t)(mk >> 32); }
        }
    }
    __syncthreads();

    // ---- stage D: fc2 + bn4 + clip, fc3 + log_softmax (k45 tail verbatim) ----
    {
        int acc0 = 0, acc1 = 0;
#pragma unroll
        for (int k = 0; k < 16; k++) {
            uint32_t w = wpf2[k * 256 + t];
            acc0 += __popc(w ^ li3[0][k]);
            acc1 += __popc(w ^ li3[1][k]);
        }
        float4 p = ((const float4*)bnp4)[t];
        float h0 = __fadd_rn((float)(512 - 2 * acc0), p.z);
        float v0 = __fadd_rn(__fmul_rn(h0, p.x), p.y);
        hbuf[0][t] = fminf(1.f, fmaxf(-1.f, v0));
        float h1 = __fadd_rn((float)(512 - 2 * acc1), p.z);
        float v1 = __fadd_rn(__fmul_rn(h1, p.x), p.y);
        hbuf[1][t] = fminf(1.f, fmaxf(-1.f, v1));
    }
    __syncthreads();
    if (t < 128) {                            // waves 0,1 -> samples b0, b0+1
        int wv2 = t >> 6, l2 = t & 63;
        float4 hv = ((const float4*)(hbuf[wv2]))[l2];
        float logits[10];
#pragma unroll
        for (int j = 0; j < 10; j++) {
            const float4* wp4 = (const float4*)(f3w + j * 256);
            float4 w4 = wp4[l2];
            float pp = hv.x * w4.x + hv.y * w4.y + hv.z * w4.z + hv.w * w4.w;
#pragma unroll
            for (int off = 32; off > 0; off >>= 1) pp += __shfl_xor(pp, off, 64);
            logits[j] = pp + f3b[j];
        }
        float mx = logits[0];
#pragma unroll
        for (int j = 1; j < 10; j++) mx = fmaxf(mx, logits[j]);
        float sum = 0.f;
#pragma unroll
        for (int j = 0; j < 10; j++) sum += expf(logits[j] - mx);
        float ls = mx + logf(sum);
        if (l2 < 10) out[(size_t)(b0 + wv2) * 10 + l2] = logits[l2] - ls;
    }
}

extern "C" void kernel_launch(void* const* d_in, const int* in_sizes, int n_in,
                              void* d_out, int out_size, void* d_ws, size_t ws_size,
                              hipStream_t stream) {
    (void)in_sizes; (void)n_in; (void)out_size; (void)ws_size;
    const float* x   = (const float*)d_in[0];
    const float* c1w = (const float*)d_in[1];
    const float* c1b = (const float*)d_in[2];
    const float* b1g = (const float*)d_in[3];
    const float* b1b = (const float*)d_in[4];
    const float* b1m = (const float*)d_in[5];
    const float* b1v = (const float*)d_in[6];
    const float* c2w = (const float*)d_in[7];
    const float* c2b = (const float*)d_in[8];
    const float* b2g = (const float*)d_in[9];
    const float* b2b = (const float*)d_in[10];
    const float* b2m = (const float*)d_in[11];
    const float* b2v = (const float*)d_in[12];
    const float* f1w = (const float*)d_in[13];
    const float* f1b = (const float*)d_in[14];
    const float* b3g = (const float*)d_in[15];
    const float* b3b = (const float*)d_in[16];
    const float* b3m = (const float*)d_in[17];
    const float* b3v = (const float*)d_in[18];
    const float* f2w = (const float*)d_in[19];
    const float* f2b = (const float*)d_in[20];
    const float* b4g = (const float*)d_in[21];
    const float* b4b = (const float*)d_in[22];
    const float* b4m = (const float*)d_in[23];
    const float* b4v = (const float*)d_in[24];
    const float* f3w = (const float*)d_in[25];
    const float* f3b = (const float*)d_in[26];
    float* out = (float*)d_out;

    uint8_t* ws = (uint8_t*)d_ws;
    uint32_t* ws1  = (uint32_t*)(ws + 0);         // [B,256] conv2 in bits  2 MB
    float*    sw1  = (float*)   (ws + 3276800);   // [32,32] signed conv1 w + bn
    uint32_t* wp2  = (uint32_t*)(ws + 3280896);   // [64,16] conv2 bits + corr
    uint32_t* wpf1 = (uint32_t*)(ws + 3284992);   // [128,512] fc1 bits^T
    uint32_t* wpf2 = (uint32_t*)(ws + 3547136);   // [16,256]  fc2 bits^T
    float*    bnp2 = (float*)   (ws + 3564032);   // [64]
    float*    bnp3 = (float*)   (ws + 3565056);   // [512]
    float*    bnp4 = (float*)   (ws + 3573248);   // [256]

    k0_pack<<<1043, 256, 0, stream>>>(c1w, c2w, f1w, f2w, c1b, c2b, f1b, f2b,
                                      b1g, b1b, b1m, b1v, b2g, b2b, b2m, b2v,
                                      b3g, b3b, b3m, b3v, b4g, b4b, b4m, b4v,
                                      sw1, wp2, wpf1, wpf2, bnp2, bnp3, bnp4);
    k1_conv1<<<BSZ, 256, 0, stream>>>(x, sw1, ws1);
    kBCD<<<BSZ / 2, 256, 0, stream>>>(ws1, wp2, bnp2, wpf1, bnp3, wpf2, bnp4,
                                      f3w, f3b, out);
}

// Round 10
// 203.391 us; speedup vs baseline: 1.0302x; 1.0302x over previous
//
#include <hip/hip_runtime.h>
#include <cstdint>

// BinarizedLeNet5 / CIFAR10, B=2048.  Round 11.
//  k1  : reverted to the proven r8 body (unroll 2, 46.6us). unroll 4 regressed
//        (54.3us, occupancy 31.6->26.4%) -- o-loop is closed, do not touch.
//  kBCD: stage C vectorized -- thread t computes fc1 outputs 2t,2t+1 via ONE
//        uint2 weight load per k (halves VMEM insts 256->128, fully coalesced).
//        li3 words reconstructed exactly via even/odd ballots + 16->32 Morton
//        interleave on lanes 0..3 (pure bit permutation). Per-output float op
//        order identical -> absmax 0.0. Stages B/D unchanged.
//  k0 unchanged.

#define BSZ 2048

__device__ __forceinline__ float sgnf(float w) {
    return (w > 0.f) ? 1.f : ((w < 0.f) ? -1.f : 0.f);
}

__device__ __forceinline__ uint32_t spread16(uint32_t x) {
    x &= 0xFFFFu;
    x = (x | (x << 8)) & 0x00FF00FFu;
    x = (x | (x << 4)) & 0x0F0F0F0Fu;
    x = (x | (x << 2)) & 0x33333333u;
    x = (x | (x << 1)) & 0x55555555u;
    return x;
}

// ---------------- k0: all packing ----------------
__global__ __launch_bounds__(256) void k0_pack(
    const float* __restrict__ c1w, const float* __restrict__ c2w,
    const float* __restrict__ f1w, const float* __restrict__ f2w,
    const float* __restrict__ c1b, const float* __restrict__ c2b,
    const float* __restrict__ f1b, const float* __restrict__ f2b,
    const float* __restrict__ b1g, const float* __restrict__ b1b,
    const float* __restrict__ b1m, const float* __restrict__ b1v,
    const float* __restrict__ b2g, const float* __restrict__ b2b,
    const float* __restrict__ b2m, const float* __restrict__ b2v,
    const float* __restrict__ b3g, const float* __restrict__ b3b,
    const float* __restrict__ b3m, const float* __restrict__ b3v,
    const float* __restrict__ b4g, const float* __restrict__ b4b,
    const float* __restrict__ b4m, const float* __restrict__ b4v,
    float* __restrict__ sw1, uint32_t* __restrict__ wp2,
    uint32_t* __restrict__ wpf1, uint32_t* __restrict__ wpf2,
    float* __restrict__ bnp2, float* __restrict__ bnp3,
    float* __restrict__ bnp4) {
    int bid = blockIdx.x, t = threadIdx.x;
    if (bid < 1024) {
        // fc1 pack: wave W covers 512 consecutive elements of row o.
        int W = bid * 4 + (t >> 6), l = t & 63;
        int o = W >> 3, chunk = W & 7;
        const float* row = f1w + (size_t)o * 4096 + chunk * 512;
        int kwb = chunk * 16;
#pragma unroll
        for (int j = 0; j < 8; j++) {
            float vj = row[j * 64 + l];
            unsigned long long mk = __ballot(vj > 0.f);
            if (l == 0) {
                wpf1[(size_t)(kwb + 2 * j) * 512 + o] = (uint32_t)mk;
                wpf1[(size_t)(kwb + 2 * j + 1) * 512 + o] = (uint32_t)(mk >> 32);
            }
        }
    } else if (bid == 1024) {
        // conv2 pack: wp2[o*16+k]: k<9 = weight bits, k=9..15 = precomputed
        // border-correction constants {R0,R2,C0,C2,t0,t2,(t6|t8<<16)}.
        __shared__ uint32_t wloc[576];
        for (int i = t; i < 576; i += 256) {
            int o = i / 9, k = i - o * 9;
            uint32_t word = 0;
            for (int c = 0; c < 32; c++)
                if (c2w[(o * 32 + c) * 9 + k] > 0.f) word |= (1u << c);
            wloc[i] = word;
        }
        __syncthreads();
        for (int i = t; i < 1024; i += 256) {
            int o = i >> 4, k = i & 15;
            const uint32_t* wr = wloc + o * 9;
            uint32_t outv;
            if (k < 9) {
                outv = wr[k];
            } else {
                int tv[9];
#pragma unroll
                for (int j = 0; j < 9; j++) tv[j] = 32 - 2 * __popc(wr[j]);
                int v = 0;
                if (k == 9)  v = tv[0] + tv[1] + tv[2];            // R0
                if (k == 10) v = tv[6] + tv[7] + tv[8];            // R2
                if (k == 11) v = tv[0] + tv[3] + tv[6];            // C0
                if (k == 12) v = tv[2] + tv[5] + tv[8];            // C2
                if (k == 13) v = tv[0];                            // t0
                if (k == 14) v = tv[2];                            // t2
                if (k == 15)
                    v = (int)(((uint32_t)(uint16_t)tv[6]) |
                              ((uint32_t)(uint16_t)tv[8] << 16));  // t6|t8
                outv = (uint32_t)v;
            }
            wp2[i] = outv;
        }
        if (t < 64) {
            float inv = __fdiv_rn(b2g[t], __fsqrt_rn(b2v[t] + 1e-5f));
            float add = __fsub_rn(b2b[t], __fmul_rn(b2m[t], inv));
            bnp2[t * 4] = inv; bnp2[t * 4 + 1] = add;
            bnp2[t * 4 + 2] = c2b[t]; bnp2[t * 4 + 3] = 0.f;
        }
    } else if (bid == 1025) {
        // conv1 signed weights, bn folded into slots 28..30 of each 32-row.
        for (int i = t; i < 1024; i += 256) {
            int o = i >> 5, r = i & 31;
            float val;
            if (r < 27) {
                val = sgnf(c1w[o * 27 + r]);
            } else if (r == 28 || r == 29 || r == 30) {
                float inv = __fdiv_rn(b1g[o], __fsqrt_rn(b1v[o] + 1e-5f));
                float add = __fsub_rn(b1b[o], __fmul_rn(b1m[o], inv));
                val = (r == 28) ? inv : ((r == 29) ? add : c1b[o]);
            } else {
                val = 0.f;
            }
            sw1[i] = val;
        }
    } else if (bid < 1042) {
        // fc2 pack: wpf2[k*256+o]
        int i = (bid - 1026) * 256 + t;       // 4096 = [16 k][256 o]
        int k = i >> 8, o = i & 255;
        const float* r = f2w + (size_t)o * 512 + k * 32;
        uint32_t word = 0;
#pragma unroll
        for (int j = 0; j < 32; j++)
            if (r[j] > 0.f) word |= (1u << j);
        wpf2[k * 256 + o] = word;
    } else {
        // bn3 + bn4 params (with fc biases folded in slot .z)
        for (int i = t; i < 512; i += 256) {
            float inv = __fdiv_rn(b3g[i], __fsqrt_rn(b3v[i] + 1e-5f));
            float add = __fsub_rn(b3b[i], __fmul_rn(b3m[i], inv));
            bnp3[i * 4] = inv; bnp3[i * 4 + 1] = add;
            bnp3[i * 4 + 2] = f1b[i]; bnp3[i * 4 + 3] = 0.f;
        }
        if (t < 256) {
            float inv = __fdiv_rn(b4g[t], __fsqrt_rn(b4v[t] + 1e-5f));
            float add = __fsub_rn(b4b[t], __fmul_rn(b4m[t], inv));
            bnp4[t * 4] = inv; bnp4[t * 4 + 1] = add;
            bnp4[t * 4 + 2] = f2b[t]; bnp4[t * 4 + 3] = 0.f;
        }
    }
}

// ---------------- k1: conv1 + pool + bn1 + sign-pack (r8 proven body) --------
__global__ __launch_bounds__(256) void k1_conv1(
    const float* __restrict__ x, const float* __restrict__ sw,
    uint32_t* __restrict__ out) {
    int b = blockIdx.x, t = threadIdx.x;
    const int TS = 36;                       // tile row stride (words)
    __shared__ float tile[3 * 34 * TS];      // rows 0..33 = conv rows -1..32
    // border zeroing: rows 0,33 cols 0..33; cols 0,33 rows 1..32  (132/channel)
#pragma unroll
    for (int q = 0; q < 2; q++) {
        int i = q * 256 + t;
        if (i < 396) {
            int c = i / 132, r = i - c * 132;
            int row, col;
            if (r < 34)      { row = 0;      col = r; }
            else if (r < 68) { row = 33;     col = r - 34; }
            else if (r < 100){ row = r - 67; col = 0; }
            else             { row = r - 99; col = 33; }
            tile[c * (34 * TS) + row * TS + col] = 0.f;
        }
    }
#pragma unroll
    for (int q = 0; q < 3; q++) {            // 768 float4 = 3 per thread
        int idx = q * 256 + t;
        int c = idx >> 8, rem = idx & 255;
        int r = rem >> 3, c4 = rem & 7;
        float4 v = ((const float4*)(x + ((size_t)b * 3 + c) * 1024 + r * 32))[c4];
        float* dst = tile + c * (34 * TS) + (r + 1) * TS + c4 * 4 + 1;
        dst[0] = v.x; dst[1] = v.y; dst[2] = v.z; dst[3] = v.w;
    }
    __syncthreads();
    int py = t >> 4, px = t & 15;
    float in[48];
#pragma unroll
    for (int c = 0; c < 3; c++)
#pragma unroll
        for (int i = 0; i < 4; i++) {
            int base = c * (34 * TS) + (2 * py + i) * TS + 2 * px;
            float2 v01 = *(const float2*)&tile[base];
            float2 v23 = *(const float2*)&tile[base + 2];
            in[c * 16 + i * 4]     = v01.x;
            in[c * 16 + i * 4 + 1] = v01.y;
            in[c * 16 + i * 4 + 2] = v23.x;
            in[c * 16 + i * 4 + 3] = v23.y;
        }
    uint32_t word = 0;
#pragma unroll 2
    for (int o = 0; o < 32; o++) {
        const float* wo = sw + o * 32;           // uniform -> s_load (x16 pairs)
        float a00 = 0.f, a01 = 0.f, a10 = 0.f, a11 = 0.f;
#pragma unroll
        for (int c = 0; c < 3; c++)
#pragma unroll
            for (int ky = 0; ky < 3; ky++)
#pragma unroll
                for (int kx = 0; kx < 3; kx++) {
                    float wv = wo[c * 9 + ky * 3 + kx];
                    a00 = fmaf(in[c * 16 + ky * 4 + kx], wv, a00);
                    a01 = fmaf(in[c * 16 + ky * 4 + kx + 1], wv, a01);
                    a10 = fmaf(in[c * 16 + (ky + 1) * 4 + kx], wv, a10);
                    a11 = fmaf(in[c * 16 + (ky + 1) * 4 + kx + 1], wv, a11);
                }
        float4 p = *(const float4*)(wo + 28);    // {inv, add, bias, 0}
        float mx = fmaxf(fmaxf(a00, a01), fmaxf(a10, a11));
        float h = __fadd_rn(mx, p.z);
        float val = __fadd_rn(__fmul_rn(h, p.x), p.y);
        word |= (val > 0.f) ? (1u << o) : 0u;
    }
    out[(size_t)b * 256 + t] = word;
}

// ---------------- conv2 helper (unchanged) ----------------
__device__ __forceinline__ int conv2_mi(
    const uint32_t* val,
    uint32_t w0, uint32_t w1, uint32_t w2, uint32_t w3, uint32_t w4,
    uint32_t w5, uint32_t w6, uint32_t w7, uint32_t w8,
    int R0, int R2, int C0, int C2, int t0, int t2, int t6, int t8,
    bool top, bool bot, bool lef, bool rig,
    bool ctl, bool ctr, bool cbl, bool cbr) {
    int P00 = __popc(val[0] ^ w0) + __popc(val[1] ^ w1) + __popc(val[2] ^ w2) +
              __popc(val[4] ^ w3) + __popc(val[5] ^ w4) + __popc(val[6] ^ w5) +
              __popc(val[8] ^ w6) + __popc(val[9] ^ w7) + __popc(val[10] ^ w8);
    int P01 = __popc(val[1] ^ w0) + __popc(val[2] ^ w1) + __popc(val[3] ^ w2) +
              __popc(val[5] ^ w3) + __popc(val[6] ^ w4) + __popc(val[7] ^ w5) +
              __popc(val[9] ^ w6) + __popc(val[10] ^ w7) + __popc(val[11] ^ w8);
    int P10 = __popc(val[4] ^ w0) + __popc(val[5] ^ w1) + __popc(val[6] ^ w2) +
              __popc(val[8] ^ w3) + __popc(val[9] ^ w4) + __popc(val[10] ^ w5) +
              __popc(val[12] ^ w6) + __popc(val[13] ^ w7) + __popc(val[14] ^ w8);
    int P11 = __popc(val[5] ^ w0) + __popc(val[6] ^ w1) + __popc(val[7] ^ w2) +
              __popc(val[9] ^ w3) + __popc(val[10] ^ w4) + __popc(val[11] ^ w5) +
              __popc(val[13] ^ w6) + __popc(val[14] ^ w7) + __popc(val[15] ^ w8);
    int s00 = 288 - 2 * P00 - ((top ? R0 : 0) + (lef ? C0 : 0) - (ctl ? t0 : 0));
    int s01 = 288 - 2 * P01 - ((top ? R0 : 0) + (rig ? C2 : 0) - (ctr ? t2 : 0));
    int s10 = 288 - 2 * P10 - ((bot ? R2 : 0) + (lef ? C0 : 0) - (cbl ? t6 : 0));
    int s11 = 288 - 2 * P11 - ((bot ? R2 : 0) + (rig ? C2 : 0) - (cbr ? t8 : 0));
    return max(max(s00, s01), max(s10, s11));
}

// ---------------- kBCD: conv2 + fc1 + fc2 + fc3, 2 samples/block ----------------
__global__ __launch_bounds__(256) void kBCD(
    const uint32_t* __restrict__ in, const uint32_t* __restrict__ wp2,
    const float* __restrict__ bnp2, const uint32_t* __restrict__ wpf1,
    const float* __restrict__ bnp3, const uint32_t* __restrict__ wpf2,
    const float* __restrict__ bnp4, const float* __restrict__ f3w,
    const float* __restrict__ f3b, float* __restrict__ out) {
    int t = threadIdx.x;
    int b0 = blockIdx.x * 2;
    const int P = 19;
    __shared__ uint32_t tile[2][18 * 19];
    __shared__ uint32_t li2[2][128];
    __shared__ uint32_t li3[2][16];
    __shared__ float hbuf[2][256];

    // ---- stage B: conv2 xnor-popc + pool + bn2 + sign (k3 2-sample body) ----
    {
        uint32_t* tf = &tile[0][0];
        for (int i = t; i < 2 * 18 * 19; i += 256) tf[i] = 0;
        __syncthreads();
        {
            int y = t >> 4, xx = t & 15;
#pragma unroll
            for (int s = 0; s < 2; s++)
                tile[s][(y + 1) * P + xx + 1] = in[(size_t)(b0 + s) * 256 + t];
        }
        __syncthreads();
        int wv = t >> 6, l = t & 63;
        int py = l >> 3, px = l & 7;
        uint32_t va[16], vb[16];
#pragma unroll
        for (int i = 0; i < 4; i++)
#pragma unroll
            for (int j = 0; j < 4; j++) {
                va[i * 4 + j] = tile[0][(2 * py + i) * P + 2 * px + j];
                vb[i * 4 + j] = tile[1][(2 * py + i) * P + 2 * px + j];
            }
        bool top = (py == 0), bot = (py == 7), lef = (px == 0), rig = (px == 7);
        bool ctl = top && lef, ctr = top && rig, cbl = bot && lef, cbr = bot && rig;
#pragma unroll 2
        for (int oi = 0; oi < 16; oi++) {
            int o = __builtin_amdgcn_readfirstlane(wv * 16 + oi);  // force SGPR
            const uint32_t* wo = wp2 + o * 16;
            uint32_t w0 = wo[0], w1 = wo[1], w2 = wo[2], w3 = wo[3], w4 = wo[4],
                     w5 = wo[5], w6 = wo[6], w7 = wo[7], w8 = wo[8];
            int R0 = (int)wo[9], R2 = (int)wo[10], C0 = (int)wo[11], C2 = (int)wo[12];
            int t0 = (int)wo[13], t2 = (int)wo[14];
            int pk = (int)wo[15];
            int t6 = (int)(short)(pk & 0xffff);
            int t8 = pk >> 16;
            float4 p = ((const float4*)bnp2)[o];
            int miA = conv2_mi(va, w0, w1, w2, w3, w4, w5, w6, w7, w8,
                               R0, R2, C0, C2, t0, t2, t6, t8,
                               top, bot, lef, rig, ctl, ctr, cbl, cbr);
            float hA = __fadd_rn((float)miA, p.z);
            float bvA = __fadd_rn(__fmul_rn(hA, p.x), p.y);
            unsigned long long mkA = __ballot(bvA > 0.f);
            int miB = conv2_mi(vb, w0, w1, w2, w3, w4, w5, w6, w7, w8,
                               R0, R2, C0, C2, t0, t2, t6, t8,
                               top, bot, lef, rig, ctl, ctr, cbl, cbr);
            float hB = __fadd_rn((float)miB, p.z);
            float bvB = __fadd_rn(__fmul_rn(hB, p.x), p.y);
            unsigned long long mkB = __ballot(bvB > 0.f);
            if (l == 0) {
                li2[0][2 * o] = (uint32_t)mkA;
                li2[0][2 * o + 1] = (uint32_t)(mkA >> 32);
                li2[1][2 * o] = (uint32_t)mkB;
                li2[1][2 * o + 1] = (uint32_t)(mkB >> 32);
            }
        }
    }
    __syncthreads();

    // ---- stage C: fc1 xnor-popc + bn3 + sign; thread t -> outputs 2t, 2t+1 ---
    // uint2 weight loads (one 8B coalesced load per k); li3 words reconstructed
    // via even/odd ballots + Morton interleave (exact bit permutation).
    {
        int o0 = 2 * t;
        float4 pE = ((const float4*)bnp3)[o0];
        float4 pO = ((const float4*)bnp3)[o0 + 1];
        int a00 = 0, a01 = 0, a10 = 0, a11 = 0;   // a[sample][even/odd]
#pragma unroll 8
        for (int k = 0; k < 128; k++) {
            uint2 w = *(const uint2*)&wpf1[k * 512 + o0];   // coalesced 8B
            uint32_t s0 = li2[0][k], s1 = li2[1][k];        // LDS broadcast
            a00 += __popc(w.x ^ s0);
            a01 += __popc(w.y ^ s0);
            a10 += __popc(w.x ^ s1);
            a11 += __popc(w.y ^ s1);
        }
        float hE0 = __fadd_rn((float)(4096 - 2 * a00), pE.z);
        float bE0 = __fadd_rn(__fmul_rn(hE0, pE.x), pE.y);
        float hO0 = __fadd_rn((float)(4096 - 2 * a01), pO.z);
        float bO0 = __fadd_rn(__fmul_rn(hO0, pO.x), pO.y);
        float hE1 = __fadd_rn((float)(4096 - 2 * a10), pE.z);
        float bE1 = __fadd_rn(__fmul_rn(hE1, pE.x), pE.y);
        float hO1 = __fadd_rn((float)(4096 - 2 * a11), pO.z);
        float bO1 = __fadd_rn(__fmul_rn(hO1, pO.x), pO.y);
        unsigned long long mE0 = __ballot(bE0 > 0.f);   // sample0 even outputs
        unsigned long long mO0 = __ballot(bO0 > 0.f);   // sample0 odd outputs
        unsigned long long mE1 = __ballot(bE1 > 0.f);   // sample1 even
        unsigned long long mO1 = __ballot(bO1 > 0.f);   // sample1 odd
        int wv = t >> 6, l = t & 63;
        if (l < 4) {
            // word 4wv+l covers outputs 128wv+32l .. +31:
            // bit 2i = even-mask bit 16l+i, bit 2i+1 = odd-mask bit 16l+i
            uint32_t aE0 = (uint32_t)(mE0 >> (16 * l)) & 0xFFFFu;
            uint32_t aO0 = (uint32_t)(mO0 >> (16 * l)) & 0xFFFFu;
            li3[0][4 * wv + l] = spread16(aE0) | (spread16(aO0) << 1);
            uint32_t aE1 = (uint32_t)(mE1 >> (16 * l)) & 0xFFFFu;
            uint32_t aO1 = (uint32_t)(mO1 >> (16 * l)) & 0xFFFFu;
            li3[1][4 * wv + l] = spread16(aE1) | (spread16(aO1) << 1);
        }
    }
    __syncthreads();

    // ---- stage D: fc2 + bn4 + clip, fc3 + log_softmax (verbatim) ----
    {
        int acc0 = 0, acc1 = 0;
#pragma unroll
        for (int k = 0; k < 16; k++) {
            uint32_t w = wpf2[k * 256 + t];
            acc0 += __popc(w ^ li3[0][k]);
            acc1 += __popc(w ^ li3[1][k]);
        }
        float4 p = ((const float4*)bnp4)[t];
        float h0 = __fadd_rn((float)(512 - 2 * acc0), p.z);
        float v0 = __fadd_rn(__fmul_rn(h0, p.x), p.y);
        hbuf[0][t] = fminf(1.f, fmaxf(-1.f, v0));
        float h1 = __fadd_rn((float)(512 - 2 * acc1), p.z);
        float v1 = __fadd_rn(__fmul_rn(h1, p.x), p.y);
        hbuf[1][t] = fminf(1.f, fmaxf(-1.f, v1));
    }
    __syncthreads();
    if (t < 128) {                            // waves 0,1 -> samples b0, b0+1
        int wv2 = t >> 6, l2 = t & 63;
        float4 hv = ((const float4*)(hbuf[wv2]))[l2];
        float logits[10];
#pragma unroll
        for (int j = 0; j < 10; j++) {
            const float4* wp4 = (const float4*)(f3w + j * 256);
            float4 w4 = wp4[l2];
            float pp = hv.x * w4.x + hv.y * w4.y + hv.z * w4.z + hv.w * w4.w;
#pragma unroll
            for (int off = 32; off > 0; off >>= 1) pp += __shfl_xor(pp, off, 64);
            logits[j] = pp + f3b[j];
        }
        float mx = logits[0];
#pragma unroll
        for (int j = 1; j < 10; j++) mx = fmaxf(mx, logits[j]);
        float sum = 0.f;
#pragma unroll
        for (int j = 0; j < 10; j++) sum += expf(logits[j] - mx);
        float ls = mx + logf(sum);
        if (l2 < 10) out[(size_t)(b0 + wv2) * 10 + l2] = logits[l2] - ls;
    }
}

extern "C" void kernel_launch(void* const* d_in, const int* in_sizes, int n_in,
                              void* d_out, int out_size, void* d_ws, size_t ws_size,
                              hipStream_t stream) {
    (void)in_sizes; (void)n_in; (void)out_size; (void)ws_size;
    const float* x   = (const float*)d_in[0];
    const float* c1w = (const float*)d_in[1];
    const float* c1b = (const float*)d_in[2];
    const float* b1g = (const float*)d_in[3];
    const float* b1b = (const float*)d_in[4];
    const float* b1m = (const float*)d_in[5];
    const float* b1v = (const float*)d_in[6];
    const float* c2w = (const float*)d_in[7];
    const float* c2b = (const float*)d_in[8];
    const float* b2g = (const float*)d_in[9];
    const float* b2b = (const float*)d_in[10];
    const float* b2m = (const float*)d_in[11];
    const float* b2v = (const float*)d_in[12];
    const float* f1w = (const float*)d_in[13];
    const float* f1b = (const float*)d_in[14];
    const float* b3g = (const float*)d_in[15];
    const float* b3b = (const float*)d_in[16];
    const float* b3m = (const float*)d_in[17];
    const float* b3v = (const float*)d_in[18];
    const float* f2w = (const float*)d_in[19];
    const float* f2b = (const float*)d_in[20];
    const float* b4g = (const float*)d_in[21];
    const float* b4b = (const float*)d_in[22];
    const float* b4m = (const float*)d_in[23];
    const float* b4v = (const float*)d_in[24];
    const float* f3w = (const float*)d_in[25];
    const float* f3b = (const float*)d_in[26];
    float* out = (float*)d_out;

    uint8_t* ws = (uint8_t*)d_ws;
    uint32_t* ws1  = (uint32_t*)(ws + 0);         // [B,256] conv2 in bits  2 MB
    float*    sw1  = (float*)   (ws + 3276800);   // [32,32] signed conv1 w + bn
    uint32_t* wp2  = (uint32_t*)(ws + 3280896);   // [64,16] conv2 bits + corr
    uint32_t* wpf1 = (uint32_t*)(ws + 3284992);   // [128,512] fc1 bits^T
    uint32_t* wpf2 = (uint32_t*)(ws + 3547136);   // [16,256]  fc2 bits^T
    float*    bnp2 = (float*)   (ws + 3564032);   // [64]
    float*    bnp3 = (float*)   (ws + 3565056);   // [512]
    float*    bnp4 = (float*)   (ws + 3573248);   // [256]

    k0_pack<<<1043, 256, 0, stream>>>(c1w, c2w, f1w, f2w, c1b, c2b, f1b, f2b,
                                      b1g, b1b, b1m, b1v, b2g, b2b, b2m, b2v,
                                      b3g, b3b, b3m, b3v, b4g, b4b, b4m, b4v,
                                      sw1, wp2, wpf1, wpf2, bnp2, bnp3, bnp4);
    k1_conv1<<<BSZ, 256, 0, stream>>>(x, sw1, ws1);
    kBCD<<<BSZ / 2, 256, 0, stream>>>(ws1, wp2, bnp2, wpf1, bnp3, wpf2, bnp4,
                                      f3w, f3b, out);
}